// Round 11
// baseline (31.695 us; speedup 1.0000x reference)
//
#include <hip/hip_runtime.h>

#define B_ 4
#define N_ 256
#define T_ 16
#define F_ 128
#define H_ 256
#define BN_ (B_ * N_)  // 1024

// ---------------------------------------------------------------------------
// lp_prep: blocks 0..127  : hbar[bn][f] = mean_t nodefeat[bn][t][f]
//          blocks 128..143: W1T[k][h] = W1[h][k]   (LDS-tiled transpose)
// (round-3 version verbatim)
// ---------------------------------------------------------------------------
__global__ __launch_bounds__(1024) void lp_prep(const float* __restrict__ nf,
                                                const float* __restrict__ W1,
                                                float* __restrict__ hbar,
                                                float* __restrict__ W1T) {
    __shared__ float sT[64][65];
    const int tid = threadIdx.x;
    if (blockIdx.x < 128) {
        const int idx = blockIdx.x * 1024 + tid;   // bn*128 + f
        const int bn  = idx >> 7;
        const int f   = idx & 127;
        const float* src = nf + (size_t)bn * (T_ * F_) + f;
        float s = 0.f;
#pragma unroll
        for (int t = 0; t < T_; ++t) s += src[t * F_];
        hbar[idx] = s * (1.0f / 16.0f);
    } else {
        const int t  = blockIdx.x - 128;  // 0..15
        const int y0 = (t >> 2) * 64;     // h-tile base
        const int x0 = (t & 3) * 64;      // k-tile base
        const int ty = tid >> 6;          // 0..15
        const int tx = tid & 63;
#pragma unroll
        for (int r = 0; r < 4; ++r)
            sT[r * 16 + ty][tx] = W1[(size_t)(y0 + r * 16 + ty) * 256 + (x0 + tx)];
        __syncthreads();
#pragma unroll
        for (int r = 0; r < 4; ++r)
            W1T[(size_t)(x0 + r * 16 + ty) * 256 + (y0 + tx)] = sT[tx][r * 16 + ty];
    }
}

// ---------------------------------------------------------------------------
// lp_gemm: block = (8-node tile, h-half), 512 threads = (kq 0..3, hl 0..127).
// W1T loads lane-coalesced; hbar via wave-uniform s_load.
// Outputs: aT[tile4][h][4] (b1 folded), cT[b][h][N].
// (round-3 version verbatim)
// ---------------------------------------------------------------------------
__global__ __launch_bounds__(512) void lp_gemm(const float* __restrict__ hbar,
                                               const float* __restrict__ W1T,
                                               const float* __restrict__ b1,
                                               float* __restrict__ aT,
                                               float* __restrict__ cT) {
    __shared__ float red[16][4][128];  // [val][kq][hl] = 32 KB

    const int tile8 = blockIdx.x >> 1;        // 0..127 -> 8 nodes
    const int h0    = (blockIdx.x & 1) * 128; // h half
    const int bn0   = tile8 * 8;
    const int b     = bn0 >> 8;
    const int tid   = threadIdx.x;
    const int kq    = __builtin_amdgcn_readfirstlane(tid >> 7);  // 0..3
    const int hl    = tid & 127;
    const int h     = h0 + hl;

    const float* wA = W1T + (size_t)(kq * 32) * H_ + h;
    const float* wC = W1T + (size_t)(F_ + kq * 32) * H_ + h;
    const float* hb = hbar + (size_t)bn0 * F_ + kq * 32;  // wave-uniform base

    float acca[8] = {0.f, 0.f, 0.f, 0.f, 0.f, 0.f, 0.f, 0.f};
    float accc[8] = {0.f, 0.f, 0.f, 0.f, 0.f, 0.f, 0.f, 0.f};

#pragma unroll 4
    for (int kk = 0; kk < 32; ++kk) {
        const float wa = wA[(size_t)kk * H_];   // coalesced over lanes
        const float wc = wC[(size_t)kk * H_];
#pragma unroll
        for (int n = 0; n < 8; ++n) {
            const float hv = hb[n * F_ + kk];   // uniform -> s_load
            acca[n] = fmaf(hv, wa, acca[n]);
            accc[n] = fmaf(hv, wc, accc[n]);
        }
    }

#pragma unroll
    for (int n = 0; n < 8; ++n) {
        red[n][kq][hl]     = acca[n];
        red[8 + n][kq][hl] = accc[n];
    }
    __syncthreads();

    const int rv = tid >> 7;  // 0..3
#pragma unroll
    for (int i = 0; i < 4; ++i) {
        const int v = rv * 4 + i;  // 0..15
        const float s = (red[v][0][hl] + red[v][1][hl]) + (red[v][2][hl] + red[v][3][hl]);
        if (v < 8) {
            const int bn = bn0 + v;
            aT[((size_t)(bn >> 2) * H_ + h) * 4 + (bn & 3)] = s + b1[h];
        } else {
            const int n = v - 8;
            cT[((size_t)b * H_ + h) * N_ + ((bn0 & 255) + n)] = s;
        }
    }
}

// ---------------------------------------------------------------------------
// lp_k2 v6: relu(x) = (x+|x|)/2 =>
//   logits[i][j] = 0.5*( sum_h |a_ih + c_jh| W2_h  + u_i + v_j ) + b2
// u_i = sum_h a_ih W2_h (prologue, shfl-reduced);
// v_j = sum_h c_jh W2_h (accumulated in-loop, 1 fma/iter).
// |x| is a free VOP3 input modifier -> 33 VALU/iter for 16 rows (vs 48).
// Grid 256 = 4 b x 16 i-tiles(16 rows) x 4 j-quarters(64 j); 512 threads =
// (ho 0..7 = 32-wide h-chunk, jl 0..63). Per-block cT = 64 KB -> 16 MB total
// L2 traffic (halved vs R10). LDS 35 KB -> 4 blocks/CU = 32 waves/CU.
// a-reads/W2 uniform -> s_load (SGPRs); ~35 VGPR, launch_bounds(512,8).
// ---------------------------------------------------------------------------
__global__ __launch_bounds__(512, 8) void lp_k2(const float* __restrict__ aT,
                                                const float* __restrict__ cT,
                                                const float* __restrict__ W2,
                                                const float* __restrict__ b2,
                                                float* __restrict__ out) {
    __shared__ float pr[8][17][64];  // [ho][row0..15 | vacc][jl] = 34.8 KB
    __shared__ float swu[16];        // u_i per local row

    const int bx  = blockIdx.x;      // 0..255
    const int b   = bx >> 6;         // 0..3
    const int rr  = bx & 63;
    const int it  = rr >> 2;         // 0..15 : i-tile of 16 rows
    const int jq  = rr & 3;          // j quarter
    const int i0  = it * 16;
    const int j0  = jq * 64;
    const int bn0 = b * N_ + i0;     // 16-aligned

    const int tid = threadIdx.x;     // 0..511
    const float* atile = aT + (size_t)(bn0 >> 2) * (H_ * 4);  // 4 consecutive tiles

    // ---- prologue: u_i = sum_h a[i][h]*W2[h]; wave w handles rows 2w,2w+1 ----
    {
        const int wv = tid >> 6;     // 0..7
        const int l  = tid & 63;
        const int r0 = 2 * wv, r1 = r0 + 1;
        const float* base0 = atile + (r0 >> 2) * 1024 + (r0 & 3);
        const float* base1 = atile + (r1 >> 2) * 1024 + (r1 & 3);
        float pa0 = 0.f, pa1 = 0.f;
#pragma unroll
        for (int e = 0; e < 4; ++e) {
            const int h  = 4 * l + e;
            const float w2 = W2[h];
            pa0 = fmaf(base0[h * 4], w2, pa0);
            pa1 = fmaf(base1[h * 4], w2, pa1);
        }
#pragma unroll
        for (int off = 32; off >= 1; off >>= 1) {
            pa0 += __shfl_xor(pa0, off, 64);
            pa1 += __shfl_xor(pa1, off, 64);
        }
        if (l == 0) { swu[r0] = pa0; swu[r1] = pa1; }
    }

    // ---- main loop ----
    const int ho = __builtin_amdgcn_readfirstlane(tid >> 6);  // 0..7
    const int jl = tid & 63;
    const int h0 = ho * 32;

    const float* crow = cT + (size_t)b * (H_ * N_) + j0 + jl;
    const float* a0 = atile;           // rows 0..3   ([h][4] layout)
    const float* a1 = atile + 1024;    // rows 4..7
    const float* a2 = atile + 2048;    // rows 8..11
    const float* a3 = atile + 3072;    // rows 12..15

    float c00 = 0.f, c01 = 0.f, c02 = 0.f, c03 = 0.f;
    float c04 = 0.f, c05 = 0.f, c06 = 0.f, c07 = 0.f;
    float c08 = 0.f, c09 = 0.f, c10 = 0.f, c11 = 0.f;
    float c12 = 0.f, c13 = 0.f, c14 = 0.f, c15 = 0.f;
    float vacc = 0.f;

#pragma unroll 4
    for (int hh = 0; hh < 32; ++hh) {
        const int h = h0 + hh;
        const float  cj = crow[(size_t)h * N_];          // coalesced over jl
        const float  w  = W2[h];                         // uniform -> s_load
        const float4 A0 = *(const float4*)(a0 + h * 4);  // uniform -> s_load_dwordx4
        const float4 A1 = *(const float4*)(a1 + h * 4);
        const float4 A2 = *(const float4*)(a2 + h * 4);
        const float4 A3 = *(const float4*)(a3 + h * 4);
        float x;
        x = A0.x + cj; c00 = fmaf(__builtin_fabsf(x), w, c00);
        x = A0.y + cj; c01 = fmaf(__builtin_fabsf(x), w, c01);
        x = A0.z + cj; c02 = fmaf(__builtin_fabsf(x), w, c02);
        x = A0.w + cj; c03 = fmaf(__builtin_fabsf(x), w, c03);
        x = A1.x + cj; c04 = fmaf(__builtin_fabsf(x), w, c04);
        x = A1.y + cj; c05 = fmaf(__builtin_fabsf(x), w, c05);
        x = A1.z + cj; c06 = fmaf(__builtin_fabsf(x), w, c06);
        x = A1.w + cj; c07 = fmaf(__builtin_fabsf(x), w, c07);
        x = A2.x + cj; c08 = fmaf(__builtin_fabsf(x), w, c08);
        x = A2.y + cj; c09 = fmaf(__builtin_fabsf(x), w, c09);
        x = A2.z + cj; c10 = fmaf(__builtin_fabsf(x), w, c10);
        x = A2.w + cj; c11 = fmaf(__builtin_fabsf(x), w, c11);
        x = A3.x + cj; c12 = fmaf(__builtin_fabsf(x), w, c12);
        x = A3.y + cj; c13 = fmaf(__builtin_fabsf(x), w, c13);
        x = A3.z + cj; c14 = fmaf(__builtin_fabsf(x), w, c14);
        x = A3.w + cj; c15 = fmaf(__builtin_fabsf(x), w, c15);
        vacc = fmaf(cj, w, vacc);                        // v_j partial
    }

    pr[ho][0][jl]  = c00;  pr[ho][1][jl]  = c01;
    pr[ho][2][jl]  = c02;  pr[ho][3][jl]  = c03;
    pr[ho][4][jl]  = c04;  pr[ho][5][jl]  = c05;
    pr[ho][6][jl]  = c06;  pr[ho][7][jl]  = c07;
    pr[ho][8][jl]  = c08;  pr[ho][9][jl]  = c09;
    pr[ho][10][jl] = c10;  pr[ho][11][jl] = c11;
    pr[ho][12][jl] = c12;  pr[ho][13][jl] = c13;
    pr[ho][14][jl] = c14;  pr[ho][15][jl] = c15;
    pr[ho][16][jl] = vacc;
    __syncthreads();

    // ---- epilogue: 1024 outputs (16 i x 64 j), 2 per thread ----
    const float bb = b2[0];
#pragma unroll
    for (int k = 0; k < 2; ++k) {
        const int o   = tid + k * 512;
        const int row = o >> 6;        // 0..15
        const int j   = o & 63;
        float s = 0.f, v = 0.f;
#pragma unroll
        for (int p = 0; p < 8; ++p) {
            s += pr[p][row][j];
            v += pr[p][16][j];
        }
        out[(size_t)(bn0 + row) * N_ + j0 + j] = 0.5f * (s + v + swu[row]) + bb;
    }
}

extern "C" void kernel_launch(void* const* d_in, const int* in_sizes, int n_in,
                              void* d_out, int out_size, void* d_ws, size_t ws_size,
                              hipStream_t stream) {
    const float* nodefeat = (const float*)d_in[0];  // [B,N,T,F]
    const float* W1       = (const float*)d_in[1];  // [H, 2F]
    const float* b1       = (const float*)d_in[2];  // [H]
    const float* W2       = (const float*)d_in[3];  // [1, H]
    const float* b2       = (const float*)d_in[4];  // [1]
    float* out = (float*)d_out;                     // [B,N,N]

    float* hbar = (float*)d_ws;                     // [1024][128]        = 512 KB
    float* W1T  = hbar + (size_t)BN_ * F_;          // [256][256]         = 256 KB
    float* aT   = W1T + 256 * 256;                  // [256 tiles][H][4]  = 1 MB
    float* cT   = aT + (size_t)256 * H_ * 4;        // [B][H][N]          = 1 MB

    lp_prep<<<144, 1024, 0, stream>>>(nodefeat, W1, hbar, W1T);
    lp_gemm<<<256, 512, 0, stream>>>(hbar, W1T, b1, aT, cT);
    lp_k2<<<256, 512, 0, stream>>>(aT, cT, W2, b2, out);
}

// Round 12
// 25.416 us; speedup vs baseline: 1.2471x; 1.2471x over previous
//
#include <hip/hip_runtime.h>

#define B_ 4
#define N_ 256
#define T_ 16
#define F_ 128
#define H_ 256
#define BN_ (B_ * N_)  // 1024

// ---------------------------------------------------------------------------
// lp_prep: blocks 0..127  : hbar[bn][f] = mean_t nodefeat[bn][t][f]
//          blocks 128..143: W1T[k][h] = W1[h][k]   (LDS-tiled transpose)
// (round-3/10 version verbatim)
// ---------------------------------------------------------------------------
__global__ __launch_bounds__(1024) void lp_prep(const float* __restrict__ nf,
                                                const float* __restrict__ W1,
                                                float* __restrict__ hbar,
                                                float* __restrict__ W1T) {
    __shared__ float sT[64][65];
    const int tid = threadIdx.x;
    if (blockIdx.x < 128) {
        const int idx = blockIdx.x * 1024 + tid;   // bn*128 + f
        const int bn  = idx >> 7;
        const int f   = idx & 127;
        const float* src = nf + (size_t)bn * (T_ * F_) + f;
        float s = 0.f;
#pragma unroll
        for (int t = 0; t < T_; ++t) s += src[t * F_];
        hbar[idx] = s * (1.0f / 16.0f);
    } else {
        const int t  = blockIdx.x - 128;  // 0..15
        const int y0 = (t >> 2) * 64;     // h-tile base
        const int x0 = (t & 3) * 64;      // k-tile base
        const int ty = tid >> 6;          // 0..15
        const int tx = tid & 63;
#pragma unroll
        for (int r = 0; r < 4; ++r)
            sT[r * 16 + ty][tx] = W1[(size_t)(y0 + r * 16 + ty) * 256 + (x0 + tx)];
        __syncthreads();
#pragma unroll
        for (int r = 0; r < 4; ++r)
            W1T[(size_t)(x0 + r * 16 + ty) * 256 + (y0 + tx)] = sT[tx][r * 16 + ty];
    }
}

// ---------------------------------------------------------------------------
// lp_gemm: block = (8-node tile, h-half), 512 threads = (kq 0..3, hl 0..127).
// W1T loads lane-coalesced; hbar via wave-uniform s_load.
// Outputs: aT[tile4][h][4] (b1 folded), cT[b][h][N].
// (round-3/10 version verbatim)
// ---------------------------------------------------------------------------
__global__ __launch_bounds__(512) void lp_gemm(const float* __restrict__ hbar,
                                               const float* __restrict__ W1T,
                                               const float* __restrict__ b1,
                                               float* __restrict__ aT,
                                               float* __restrict__ cT) {
    __shared__ float red[16][4][128];  // [val][kq][hl] = 32 KB

    const int tile8 = blockIdx.x >> 1;        // 0..127 -> 8 nodes
    const int h0    = (blockIdx.x & 1) * 128; // h half
    const int bn0   = tile8 * 8;
    const int b     = bn0 >> 8;
    const int tid   = threadIdx.x;
    const int kq    = __builtin_amdgcn_readfirstlane(tid >> 7);  // 0..3
    const int hl    = tid & 127;
    const int h     = h0 + hl;

    const float* wA = W1T + (size_t)(kq * 32) * H_ + h;
    const float* wC = W1T + (size_t)(F_ + kq * 32) * H_ + h;
    const float* hb = hbar + (size_t)bn0 * F_ + kq * 32;  // wave-uniform base

    float acca[8] = {0.f, 0.f, 0.f, 0.f, 0.f, 0.f, 0.f, 0.f};
    float accc[8] = {0.f, 0.f, 0.f, 0.f, 0.f, 0.f, 0.f, 0.f};

#pragma unroll 4
    for (int kk = 0; kk < 32; ++kk) {
        const float wa = wA[(size_t)kk * H_];   // coalesced over lanes
        const float wc = wC[(size_t)kk * H_];
#pragma unroll
        for (int n = 0; n < 8; ++n) {
            const float hv = hb[n * F_ + kk];   // uniform -> s_load
            acca[n] = fmaf(hv, wa, acca[n]);
            accc[n] = fmaf(hv, wc, accc[n]);
        }
    }

#pragma unroll
    for (int n = 0; n < 8; ++n) {
        red[n][kq][hl]     = acca[n];
        red[8 + n][kq][hl] = accc[n];
    }
    __syncthreads();

    const int rv = tid >> 7;  // 0..3
#pragma unroll
    for (int i = 0; i < 4; ++i) {
        const int v = rv * 4 + i;  // 0..15
        const float s = (red[v][0][hl] + red[v][1][hl]) + (red[v][2][hl] + red[v][3][hl]);
        if (v < 8) {
            const int bn = bn0 + v;
            aT[((size_t)(bn >> 2) * H_ + h) * 4 + (bn & 3)] = s + b1[h];
        } else {
            const int n = v - 8;
            cT[((size_t)b * H_ + h) * N_ + ((bn0 & 255) + n)] = s;
        }
    }
}

// ---------------------------------------------------------------------------
// lp_k2 v7: R10's k2 (grid 512 = 4b x 32 i-tiles(8) x 4 jq(64); 1024 thr =
// (ho 0..15 -> 16-h chunk, jl 0..63); 2 blocks/CU = 32 waves/CU) with ONLY
// the inner body changed to the relu identity:
//   relu(x) = (x+|x|)/2  =>  out = 0.5*(sum|a+c|w + u_i + v_j) + b2
// |x| is a free VOP3 input modifier: 8 add + 8 abs-fma + 1 vacc-fma =
// 17 VALU/iter (was 24). Loads identical to R10 (1 cj dword + 2 uniform
// s_load_dwordx4 + W2). u_i: 8-wave shfl prologue; v_j: summed in epilogue.
// ---------------------------------------------------------------------------
__global__ __launch_bounds__(1024) void lp_k2(const float* __restrict__ aT,
                                              const float* __restrict__ cT,
                                              const float* __restrict__ W2,
                                              const float* __restrict__ b2,
                                              float* __restrict__ out) {
    __shared__ float pr[16][9][64];  // [ho][row0..7 | vacc][jl] = 36.9 KB
    __shared__ float swu[8];         // u_i per local row

    const int bx  = blockIdx.x;      // 0..511
    const int b   = bx >> 7;         // 0..3
    const int rr  = bx & 127;
    const int it  = rr >> 2;         // 0..31 : i-tile of 8 rows
    const int jq  = rr & 3;          // j quarter
    const int i0  = it * 8;
    const int j0  = jq * 64;
    const int bn0 = b * N_ + i0;     // 8-aligned

    const int tid = threadIdx.x;
    const float* a0 = aT + (size_t)(bn0 >> 2) * (H_ * 4);      // rows 0..3
    const float* a1 = a0 + H_ * 4;                             // rows 4..7

    // ---- prologue: u_r = sum_h a[r][h]*W2[h]; wave w (0..7) -> row w ----
    if (tid < 512) {
        const int wv = tid >> 6;     // 0..7 = local row
        const int l  = tid & 63;
        const float* base = (wv < 4 ? a0 : a1) + (wv & 3);
        float pa = 0.f;
#pragma unroll
        for (int e = 0; e < 4; ++e) {
            const int h = 4 * l + e;
            pa = fmaf(base[h * 4], W2[h], pa);
        }
#pragma unroll
        for (int off = 32; off >= 1; off >>= 1)
            pa += __shfl_xor(pa, off, 64);
        if (l == 0) swu[wv] = pa;
    }

    // ---- main loop (R10 structure, abs-trick body) ----
    const int ho = __builtin_amdgcn_readfirstlane(tid >> 6);  // 0..15
    const int jl = tid & 63;
    const int h0 = ho * 16;

    const float* crow = cT + (size_t)b * (H_ * N_) + j0 + jl;

    float acc0 = 0.f, acc1 = 0.f, acc2 = 0.f, acc3 = 0.f;
    float acc4 = 0.f, acc5 = 0.f, acc6 = 0.f, acc7 = 0.f;
    float vacc = 0.f;

#pragma unroll 4
    for (int hh = 0; hh < 16; ++hh) {
        const int h = h0 + hh;
        const float  cj  = crow[(size_t)h * N_];           // coalesced over jl
        const float  w   = W2[h];                          // uniform -> s_load
        const float4 av0 = *(const float4*)(a0 + h * 4);   // uniform -> s_load
        const float4 av1 = *(const float4*)(a1 + h * 4);   // uniform -> s_load
        float x;
        x = av0.x + cj; acc0 = fmaf(__builtin_fabsf(x), w, acc0);
        x = av0.y + cj; acc1 = fmaf(__builtin_fabsf(x), w, acc1);
        x = av0.z + cj; acc2 = fmaf(__builtin_fabsf(x), w, acc2);
        x = av0.w + cj; acc3 = fmaf(__builtin_fabsf(x), w, acc3);
        x = av1.x + cj; acc4 = fmaf(__builtin_fabsf(x), w, acc4);
        x = av1.y + cj; acc5 = fmaf(__builtin_fabsf(x), w, acc5);
        x = av1.z + cj; acc6 = fmaf(__builtin_fabsf(x), w, acc6);
        x = av1.w + cj; acc7 = fmaf(__builtin_fabsf(x), w, acc7);
        vacc = fmaf(cj, w, vacc);                          // v_j partial
    }

    pr[ho][0][jl] = acc0;
    pr[ho][1][jl] = acc1;
    pr[ho][2][jl] = acc2;
    pr[ho][3][jl] = acc3;
    pr[ho][4][jl] = acc4;
    pr[ho][5][jl] = acc5;
    pr[ho][6][jl] = acc6;
    pr[ho][7][jl] = acc7;
    pr[ho][8][jl] = vacc;
    __syncthreads();

    // ---- epilogue: 512 outputs (8 i x 64 j) ----
    if (tid < 512) {
        const int oi = tid >> 6;   // 0..7
        const int oj = tid & 63;
        float s = 0.f, v = 0.f;
#pragma unroll
        for (int o = 0; o < 16; ++o) {
            s += pr[o][oi][oj];
            v += pr[o][8][oj];
        }
        out[(size_t)(bn0 + oi) * N_ + j0 + oj] = 0.5f * (s + v + swu[oi]) + b2[0];
    }
}

extern "C" void kernel_launch(void* const* d_in, const int* in_sizes, int n_in,
                              void* d_out, int out_size, void* d_ws, size_t ws_size,
                              hipStream_t stream) {
    const float* nodefeat = (const float*)d_in[0];  // [B,N,T,F]
    const float* W1       = (const float*)d_in[1];  // [H, 2F]
    const float* b1       = (const float*)d_in[2];  // [H]
    const float* W2       = (const float*)d_in[3];  // [1, H]
    const float* b2       = (const float*)d_in[4];  // [1]
    float* out = (float*)d_out;                     // [B,N,N]

    float* hbar = (float*)d_ws;                     // [1024][128]        = 512 KB
    float* W1T  = hbar + (size_t)BN_ * F_;          // [256][256]         = 256 KB
    float* aT   = W1T + 256 * 256;                  // [256 tiles][H][4]  = 1 MB
    float* cT   = aT + (size_t)256 * H_ * 4;        // [B][H][N]          = 1 MB

    lp_prep<<<144, 1024, 0, stream>>>(nodefeat, W1, hbar, W1T);
    lp_gemm<<<256, 512, 0, stream>>>(hbar, W1T, b1, aT, cT);
    lp_k2<<<512, 1024, 0, stream>>>(aT, cT, W2, b2, out);
}